// Round 7
// baseline (71.957 us; speedup 1.0000x reference)
//
#include <hip/hip_runtime.h>
#include <math.h>

// Problem constants (fixed by the reference)
constexpr int IN_DIM  = 128;
constexpr int OUT_DIM = 128;
constexpr int BATCH   = 512;
// Tiling (R4 config — best measured, 70.58 us total): block = 16 n x 32 o x 16 i
// grid = 32 n-tiles x 4 o-tiles x 8 i-chunks = 1024 blocks (4/CU, 16 waves/CU).
// Sweep evidence: R5 (64n tile, 1 blk/CU, 3 B/FMA) and R6 (2n x 2o, 2 blk/CU,
// 4 B/FMA) both ~1 us SLOWER despite lower LDS traffic -> the main loop is
// TLP/issue-bound, not LDS-data-bound; 16 waves/CU wins.
constexpr int TN = 16;
constexpr int TO = 32;
constexpr int IC = 16;
constexpr int NCHUNK = 8;
constexpr int TOP = TO + 1;   // +1 pad: breaks transpose-store bank conflicts

// out[n,o] = sum_i mask[s]*( scale_base[s]*silu(x[n,i])
//                          + scale_sp[s]*sum_j B_j(x[n,i])*coef[s,j] ), s=o*128+i
__global__ __launch_bounds__(256, 2) void kan_main(
    const float* __restrict__ x,          // [512][128]
    const float* __restrict__ grid,       // [16384][6] (rows identical)
    const float* __restrict__ coef,       // [16384][8]
    const float* __restrict__ scale_base, // [16384]
    const float* __restrict__ scale_sp,   // [16384]
    const float* __restrict__ mask,       // [16384]
    float* __restrict__ part)             // [8][512][128] partials in d_ws
{
    __shared__ float4 Cs0[IC * TOP];      // coef j0..3 * ssp * mask, [i][o] pad (8.4 KB)
    __shared__ float4 Cs1[IC * TOP];      // coef j4..7                          (8.4 KB)
    __shared__ float4 Ps4[TN * IC * 2];   // basis fragments [n][i][2]           (8 KB)
    __shared__ float  Vb[IC * TOP];       // scale_base*mask, [i][o] pad         (2.1 KB)
    __shared__ float  Pb[IC * TN];        // silu(x), [i][n] (broadcast reads)   (1 KB)

    const int t  = threadIdx.x;
    const int b  = blockIdx.x;
    const int ic = b & 7;
    const int ot = (b >> 3) & 3;
    const int nt = b >> 5;
    const int i0 = ic * IC;
    const int o0 = ot * TO;
    const int n0 = nt * TN;

    // ---- knots from row 0 (all 16384 grid rows identical, uniform spacing h):
    // t_ext = [g0-3h..g0-h, g0..g5, g5+h..g5+3h], h=(g5-g0)/5
    const float g0 = grid[0];
    const float g5 = grid[5];
    const float h  = (g5 - g0) * 0.2f;
    float tk[12];
    tk[0] = g0 - 3.f * h; tk[1] = g0 - 2.f * h; tk[2] = g0 - h;
    tk[3] = grid[0]; tk[4] = grid[1]; tk[5] = grid[2];
    tk[6] = grid[3]; tk[7] = grid[4]; tk[8] = grid[5];
    tk[9] = g5 + h; tk[10] = g5 + 2.f * h; tk[11] = g5 + 3.f * h;
    // Uniform knots: every Cox-de Boor denominator is exactly r*h (>=h>>1e-14,
    // so the reference's max() guard is a no-op). One divide replaces 54.
    const float inv1 = 1.0f / h;
    const float invr[3] = {inv1, inv1 * 0.5f, inv1 * (1.0f / 3.0f)};

    // ---- phase 1: one basis eval per thread (16 n x 16 i = 256)
    {
        const int nl = t >> 4;
        const int il = t & 15;
        const float xv = x[(n0 + nl) * IN_DIM + i0 + il];

        float B[11];
        #pragma unroll
        for (int j = 0; j < 11; j++)
            B[j] = (xv >= tk[j] && xv < tk[j + 1]) ? 1.0f : 0.0f;
        #pragma unroll
        for (int r = 1; r <= 3; r++) {
            const float iv = invr[r - 1];
            #pragma unroll
            for (int j = 0; j + r < 11; j++)
                B[j] = (xv - tk[j]) * iv * B[j] + (tk[j + r + 1] - xv) * iv * B[j + 1];
        }
        Ps4[(nl * IC + il) * 2 + 0] = make_float4(B[0], B[1], B[2], B[3]);
        Ps4[(nl * IC + il) * 2 + 1] = make_float4(B[4], B[5], B[6], B[7]);
        Pb[il * TN + nl] = xv / (1.0f + __expf(-xv));   // silu, [i][n]
    }

    // ---- stage coef premultiplied by scale_sp*mask.
    // Global: 32 consecutive float4 per o-row -> fully coalesced 512B groups.
    // LDS [i][o] padded (TOP=33): transpose-store 2-way (free), reads clean.
    #pragma unroll
    for (int r = 0; r < 4; r++) {
        const int fi = r * 256 + t;
        const int o  = fi >> 5;         // 8 o-rows per rep
        const int w  = fi & 31;         // 32 f4 within the row (16 i x 2 halves)
        const int i  = w >> 1;
        const int hh = w & 1;
        const int s  = (o0 + o) * IN_DIM + i0 + i;
        float4 c = ((const float4*)coef)[(size_t)s * 2 + hh];
        const float v = scale_sp[s] * mask[s];
        c.x *= v; c.y *= v; c.z *= v; c.w *= v;
        if (hh) Cs1[i * TOP + o] = c; else Cs0[i * TOP + o] = c;
    }
    // ---- stage scale_base*mask: [i][o] padded
    #pragma unroll
    for (int r = 0; r < 2; r++) {
        const int v = r * 256 + t;
        const int o = v >> 4;           // coalesced global reads along i
        const int i = v & 15;
        const int s = (o0 + o) * IN_DIM + i0 + i;
        Vb[i * TOP + o] = scale_base[s] * mask[s];
    }
    __syncthreads();

    // ---- main: thread owns (nA=t>>5, o=t&31) and (nB=nA+8, o); pure LDS+FMA.
    // Cs/Vb reads conflict-free (consecutive-o lanes); Ps4/Pb are 2-address
    // wave broadcasts (free per m136).
    const int o  = t & 31;
    const int nA = t >> 5;      // 0..7
    const int nB = nA + 8;      // 8..15
    const float4* __restrict__ psA = &Ps4[nA * IC * 2];
    const float4* __restrict__ psB = &Ps4[nB * IC * 2];

    float accA = 0.f, accB = 0.f;
    #pragma unroll
    for (int i = 0; i < IC; i++) {
        const float4 c0 = Cs0[i * TOP + o];
        const float4 c1 = Cs1[i * TOP + o];
        const float4 a0 = psA[2 * i];
        const float4 a1 = psA[2 * i + 1];
        const float4 b0 = psB[2 * i];
        const float4 b1 = psB[2 * i + 1];
        const float vb  = Vb[i * TOP + o];
        const float pbA = Pb[i * TN + nA];
        const float pbB = Pb[i * TN + nB];
        accA += c0.x * a0.x + c0.y * a0.y + c0.z * a0.z + c0.w * a0.w
              + c1.x * a1.x + c1.y * a1.y + c1.z * a1.z + c1.w * a1.w
              + vb * pbA;
        accB += c0.x * b0.x + c0.y * b0.y + c0.z * b0.z + c0.w * b0.w
              + c1.x * b1.x + c1.y * b1.y + c1.z * b1.z + c1.w * b1.w
              + vb * pbB;
    }
    // coalesced partial stores (lanes consecutive in o)
    part[((size_t)ic * BATCH + (n0 + nA)) * OUT_DIM + o0 + o] = accA;
    part[((size_t)ic * BATCH + (n0 + nB)) * OUT_DIM + o0 + o] = accB;
}

// Sum the 8 i-chunk partials. float4 lanes: 16K threads, L2-resident.
__global__ __launch_bounds__(256) void kan_reduce(
    const float4* __restrict__ part,   // [8][16384] f4
    float4* __restrict__ out)          // [16384] f4
{
    const int cell = blockIdx.x * 256 + threadIdx.x;
    float4 s = part[cell];
    #pragma unroll
    for (int c = 1; c < NCHUNK; c++) {
        const float4 v = part[c * (BATCH * OUT_DIM / 4) + cell];
        s.x += v.x; s.y += v.y; s.z += v.z; s.w += v.w;
    }
    out[cell] = s;
}

extern "C" void kernel_launch(void* const* d_in, const int* in_sizes, int n_in,
                              void* d_out, int out_size, void* d_ws, size_t ws_size,
                              hipStream_t stream) {
    const float* x          = (const float*)d_in[0];
    const float* grid       = (const float*)d_in[1];
    const float* coef       = (const float*)d_in[2];
    const float* scale_base = (const float*)d_in[3];
    const float* scale_sp   = (const float*)d_in[4];
    const float* mask       = (const float*)d_in[5];
    float* out  = (float*)d_out;
    float* part = (float*)d_ws;   // 8*512*128*4 = 2 MB << ws_size

    // grid = 32 n-tiles x 4 o-tiles x 8 i-chunks = 1024 blocks (4/CU)
    kan_main<<<dim3(1024), dim3(256), 0, stream>>>(
        x, grid, coef, scale_base, scale_sp, mask, part);
    kan_reduce<<<dim3(BATCH * OUT_DIM / 4 / 256), dim3(256), 0, stream>>>(
        (const float4*)part, (float4*)out);
}